// Round 2
// baseline (664.543 us; speedup 1.0000x reference)
//
#include <hip/hip_runtime.h>
#include <hip/hip_bf16.h>
#include <type_traits>

// PointNetConv on MI355X (gfx950).
//   K0 detect   : sniff dtype of x (bf16 vs f32 bit patterns) -> flag in ws
//   K1 init     : out_u[N*128] = key(-inf)
//   K2 node_gemm<T,false>: xw1b = bf16(x @ W1[0:128] + b1)   (stored in d_out as scratch!)
//   K3 edge<T>  : h1 = relu(xw1b[row] + rel@W1p); h2 = h1@W2 + b2 (MFMA);
//                 atomicMax(out_u[col], key(h2))
//   K4 node_gemm<T,true> : d_out = T(val(out_u) + x @ Wr + br)
//
// Both <bf16> and <float> variants of K2/K3/K4 are launched; the wrong one
// early-exits on the flag. Workspace: [0, N*512) out_u uint32; flag at N*512.

typedef __bf16 bf16_t;
typedef __bf16 bf16x8 __attribute__((ext_vector_type(8)));
typedef float  f32x4  __attribute__((ext_vector_type(4)));

#define NEG_INF_KEY 0x007FFFFFu   // key(-inf) = ~0xFF800000

__device__ __forceinline__ unsigned key_of(float f) {
  unsigned u = __float_as_uint(f);
  return (u & 0x80000000u) ? ~u : (u | 0x80000000u);   // monotone float->uint
}
__device__ __forceinline__ float val_of(unsigned k) {
  if (k == NEG_INF_KEY) return 0.f;                     // empty segment -> 0
  return (k & 0x80000000u) ? __uint_as_float(k & 0x7FFFFFFFu) : __uint_as_float(~k);
}

// --- K0: dtype sniffer. Low 16-bit halves of f32 words are ~uniform mantissa
// bits; of bf16-pair words they are bf16 N(0,1) samples with exp in [0x68,0x88].
__global__ void detect_kernel(const unsigned* __restrict__ xw, int* __restrict__ flag) {
  int lane = threadIdx.x;            // 64 threads
  int cnt = 0;
#pragma unroll
  for (int i = 0; i < 4; ++i) {
    unsigned w = xw[lane * 4 + i];
    unsigned e = (w >> 7) & 0xFFu;   // exponent field of the LOW bf16 half
    cnt += (e >= 0x68u && e <= 0x88u) ? 1 : 0;
  }
#pragma unroll
  for (int off = 32; off > 0; off >>= 1) cnt += __shfl_down(cnt, off, 64);
  if (lane == 0) *flag = (cnt >= 128) ? 0 : 1;   // 0 = bf16, 1 = f32
}

__global__ __launch_bounds__(256) void init_out_kernel(unsigned* __restrict__ out_u, int total4) {
  int i = blockIdx.x * 256 + threadIdx.x;
  if (i < total4) {
    uint4 v; v.x = v.y = v.z = v.w = NEG_INF_KEY;
    ((uint4*)out_u)[i] = v;
  }
}

template <typename T>
__device__ __forceinline__ bf16x8 load_frag8(const T* p) {
  bf16x8 r;
  if constexpr (std::is_same<T, float>::value) {
    float4 a = *(const float4*)p;
    float4 b = *(const float4*)(p + 4);
    r[0] = (bf16_t)a.x; r[1] = (bf16_t)a.y; r[2] = (bf16_t)a.z; r[3] = (bf16_t)a.w;
    r[4] = (bf16_t)b.x; r[5] = (bf16_t)b.y; r[6] = (bf16_t)b.z; r[7] = (bf16_t)b.w;
  } else {
    r = *(const bf16x8*)p;
  }
  return r;
}

// ---------------------------------------------------------------------------
// Node GEMM: 64 nodes/block, 16 nodes/wave, MFMA 16x16x32 bf16.
// FINAL=false: xw1b(d_out scratch, bf16) = x @ W + bias
// FINAL=true : d_out(T) = val(out_u) + x @ W + bias
// ---------------------------------------------------------------------------
template <typename T, bool FINAL>
__global__ __launch_bounds__(256) void node_gemm_kernel(
    const T* __restrict__ xin, const T* __restrict__ W,
    const T* __restrict__ bias, const unsigned* __restrict__ out_u,
    void* __restrict__ dst, const int* __restrict__ flag, int N)
{
  constexpr bool IS_F32 = std::is_same<T, float>::value;
  if ((*flag != 0) != IS_F32) return;   // wrong-dtype variant: bail

  __shared__ bf16_t ws_[8][4][64][8];  // [nt][kt][lane][j] : 32 KB, B-fragment-major
  __shared__ float  bs_[128];

  const int tid = threadIdx.x;
  for (int it = tid; it < 8 * 4 * 64; it += 256) {
    int nt = it >> 8, kt = (it >> 6) & 3, l = it & 63;
    int n = nt * 16 + (l & 15), quad = l >> 4;
    bf16x8 v;
#pragma unroll
    for (int j = 0; j < 8; ++j) v[j] = (bf16_t)(float)W[(kt * 32 + quad * 8 + j) * 128 + n];
    *(bf16x8*)&ws_[nt][kt][l][0] = v;
  }
  if (tid < 128) bs_[tid] = (float)bias[tid];
  __syncthreads();

  const int w = tid >> 6, lane = tid & 63;
  const int m15 = lane & 15, quad = lane >> 4;

  int node_a = blockIdx.x * 64 + w * 16 + m15;
  const T* xrow = xin + (long)min(node_a, N - 1) * 128;  // clamped rows are store-guarded
  bf16x8 a[4];
#pragma unroll
  for (int kt = 0; kt < 4; ++kt)
    a[kt] = load_frag8(xrow + kt * 32 + quad * 8);

  f32x4 acc[8];
#pragma unroll
  for (int nt = 0; nt < 8; ++nt) acc[nt] = (f32x4){0.f, 0.f, 0.f, 0.f};
#pragma unroll
  for (int nt = 0; nt < 8; ++nt)
#pragma unroll
    for (int kt = 0; kt < 4; ++kt)
      acc[nt] = __builtin_amdgcn_mfma_f32_16x16x32_bf16(
          a[kt], *(const bf16x8*)&ws_[nt][kt][lane][0], acc[nt], 0, 0, 0);

  // C/D: col = lane&15 (cout), row = quad*4 + r (node)
#pragma unroll
  for (int r = 0; r < 4; ++r) {
    int node = blockIdx.x * 64 + w * 16 + quad * 4 + r;
    if (node < N) {
#pragma unroll
      for (int nt = 0; nt < 8; ++nt) {
        int c = nt * 16 + m15;
        float v = acc[nt][r] + bs_[c];
        long idx = (long)node * 128 + c;
        if constexpr (FINAL) {
          v += val_of(out_u[idx]);
          if constexpr (IS_F32) ((float*)dst)[idx] = v;
          else                  ((bf16_t*)dst)[idx] = (bf16_t)v;
        } else {
          ((bf16_t*)dst)[idx] = (bf16_t)v;   // xw1b scratch is always bf16
        }
      }
    }
  }
}

// ---------------------------------------------------------------------------
// Edge kernel: 64 edges/tile, 16 edges/wave; h1 built in registers in
// A-operand layout; h1 @ W2 via MFMA; atomicMax(key) scatter.
// ---------------------------------------------------------------------------
template <typename T>
__global__ __launch_bounds__(256) void edge_kernel(
    const int* __restrict__ eidx, const T* __restrict__ pos,
    const bf16_t* __restrict__ xw1b, const T* __restrict__ W1,
    const T* __restrict__ W2, const T* __restrict__ b2,
    unsigned* __restrict__ out_u, const int* __restrict__ flag,
    int E, int numTiles)
{
  constexpr bool IS_F32 = std::is_same<T, float>::value;
  if ((*flag != 0) != IS_F32) return;

  __shared__ bf16_t w2s[8][4][64][8];  // 32 KB, B-fragment-major
  __shared__ float  w1ps[3][128];      // pos rows of W1 (rows 128..130)
  __shared__ float  b2s[128];
  __shared__ float  rels[64][3];
  __shared__ int    rows_s[64];
  __shared__ int    cols_s[64];

  const int tid = threadIdx.x;
  for (int it = tid; it < 8 * 4 * 64; it += 256) {
    int nt = it >> 8, kt = (it >> 6) & 3, l = it & 63;
    int n = nt * 16 + (l & 15), quad = l >> 4;
    bf16x8 v;
#pragma unroll
    for (int j = 0; j < 8; ++j) v[j] = (bf16_t)(float)W2[(kt * 32 + quad * 8 + j) * 128 + n];
    *(bf16x8*)&w2s[nt][kt][l][0] = v;
  }
  for (int it = tid; it < 384; it += 256) {
    int d = it >> 7, c = it & 127;
    w1ps[d][c] = (float)W1[(128 + d) * 128 + c];
  }
  if (tid < 128) b2s[tid] = (float)b2[tid];
  __syncthreads();

  const int w = tid >> 6, lane = tid & 63;
  const int m15 = lane & 15, quad = lane >> 4;

  float biasv[8];
#pragma unroll
  for (int nt = 0; nt < 8; ++nt) biasv[nt] = b2s[nt * 16 + m15];

  for (int tb = blockIdx.x; tb < numTiles; tb += gridDim.x) {
    long e0 = (long)tb * 64;
    if (tid < 64) {
      long e = e0 + tid;
      int r = 0, cn = -1;
      float r0 = 0.f, r1 = 0.f, r2 = 0.f;
      if (e < E) {
        r  = eidx[e];
        cn = eidx[E + e];
        r0 = (float)pos[r * 3 + 0] - (float)pos[cn * 3 + 0];
        r1 = (float)pos[r * 3 + 1] - (float)pos[cn * 3 + 1];
        r2 = (float)pos[r * 3 + 2] - (float)pos[cn * 3 + 2];
      }
      rows_s[tid] = r; cols_s[tid] = cn;
      rels[tid][0] = r0; rels[tid][1] = r1; rels[tid][2] = r2;
    }
    __syncthreads();

    // h1 A-fragment: edge m = lane&15 of this wave, k = kt*32 + quad*8 + j
    const int mloc = w * 16 + m15;
    const int row  = rows_s[mloc];
    const float p0 = rels[mloc][0], p1 = rels[mloc][1], p2 = rels[mloc][2];
    const bf16_t* xrow = xw1b + (long)row * 128;

    bf16x8 a[4];
#pragma unroll
    for (int kt = 0; kt < 4; ++kt) {
      const int j0 = kt * 32 + quad * 8;
      bf16x8 xv = *(const bf16x8*)(xrow + j0);
      bf16x8 av;
#pragma unroll
      for (int j = 0; j < 8; ++j) {
        float h = (float)xv[j] + p0 * w1ps[0][j0 + j] + p1 * w1ps[1][j0 + j] + p2 * w1ps[2][j0 + j];
        av[j] = (bf16_t)fmaxf(h, 0.f);
      }
      a[kt] = av;
    }

    f32x4 acc[8];
#pragma unroll
    for (int nt = 0; nt < 8; ++nt) acc[nt] = (f32x4){0.f, 0.f, 0.f, 0.f};
#pragma unroll
    for (int nt = 0; nt < 8; ++nt)
#pragma unroll
      for (int kt = 0; kt < 4; ++kt)
        acc[nt] = __builtin_amdgcn_mfma_f32_16x16x32_bf16(
            a[kt], *(const bf16x8*)&w2s[nt][kt][lane][0], acc[nt], 0, 0, 0);

    // D row = quad*4+r (edge), col = nt*16+m15 (cout).
    // Per quad: 16 lanes hit 16 consecutive uints (64B) of one node row.
#pragma unroll
    for (int r = 0; r < 4; ++r) {
      int node = cols_s[w * 16 + quad * 4 + r];
      if (node >= 0) {
        unsigned* dstrow = out_u + (long)node * 128 + m15;
#pragma unroll
        for (int nt = 0; nt < 8; ++nt) {
          unsigned k = key_of(acc[nt][r] + biasv[nt]);
          atomicMax(dstrow + nt * 16, k);
        }
      }
    }
    __syncthreads();  // protect rows_s/cols_s/rels before next tile
  }
}

extern "C" void kernel_launch(void* const* d_in, const int* in_sizes, int n_in,
                              void* d_out, int out_size, void* d_ws, size_t ws_size,
                              hipStream_t stream) {
  (void)n_in; (void)ws_size; (void)out_size;
  const void* x   = d_in[0];
  const void* pos = d_in[1];
  const int*  eix = (const int*)d_in[2];
  const void* W1  = d_in[3];  // 131 x 128; rows 0..127 = W1x, 128..130 = W1p
  const void* b1  = d_in[4];
  const void* W2  = d_in[5];
  const void* b2  = d_in[6];
  const void* Wr  = d_in[7];
  const void* br  = d_in[8];

  const int N = in_sizes[0] / 128;
  const int E = in_sizes[2] / 2;

  unsigned* out_u = (unsigned*)d_ws;
  int*      flag  = (int*)((char*)d_ws + (size_t)N * 512);
  bf16_t*   xw1b  = (bf16_t*)d_out;   // d_out doubles as bf16 scratch until K4

  detect_kernel<<<1, 64, 0, stream>>>((const unsigned*)x, flag);

  const int total4 = N * 32;  // N*128/4 uint4 stores
  init_out_kernel<<<(total4 + 255) / 256, 256, 0, stream>>>(out_u, total4);

  const int nodeBlocks = (N + 63) / 64;
  node_gemm_kernel<bf16_t, false><<<nodeBlocks, 256, 0, stream>>>(
      (const bf16_t*)x, (const bf16_t*)W1, (const bf16_t*)b1, nullptr, xw1b, flag, N);
  node_gemm_kernel<float, false><<<nodeBlocks, 256, 0, stream>>>(
      (const float*)x, (const float*)W1, (const float*)b1, nullptr, xw1b, flag, N);

  const int numTiles = (E + 63) / 64;
  edge_kernel<bf16_t><<<1024, 256, 0, stream>>>(
      eix, (const bf16_t*)pos, xw1b, (const bf16_t*)W1, (const bf16_t*)W2,
      (const bf16_t*)b2, out_u, flag, E, numTiles);
  edge_kernel<float><<<1024, 256, 0, stream>>>(
      eix, (const float*)pos, xw1b, (const float*)W1, (const float*)W2,
      (const float*)b2, out_u, flag, E, numTiles);

  node_gemm_kernel<bf16_t, true><<<nodeBlocks, 256, 0, stream>>>(
      (const bf16_t*)x, (const bf16_t*)Wr, (const bf16_t*)br, out_u, d_out, flag, N);
  node_gemm_kernel<float, true><<<nodeBlocks, 256, 0, stream>>>(
      (const float*)x, (const float*)Wr, (const float*)br, out_u, d_out, flag, N);
}